// Round 1
// baseline (1299.839 us; speedup 1.0000x reference)
//
#include <hip/hip_runtime.h>
#include <math.h>

#define NBLK  11
#define NAGG  4
#define NFILT 32
#define NPROP 20
#define BB    128
#define VV    1024
#define FIN   10
#define TPB   512
#define BN_EPS 1e-3f

__device__ __forceinline__ float fast_tanh(float x){
  float a = fabsf(x);
  float e = __expf(-2.0f * a);
  float r = (1.0f - e) / (1.0f + e);
  return copysignf(r, x);
}

__global__ __launch_bounds__(TPB, 2) void garnet_fused(
    const float* __restrict__ x,
    const float* __restrict__ bn0_g, const float* __restrict__ bn0_b,
    const float* __restrict__ bn0_m, const float* __restrict__ bn0_v,
    const float* __restrict__ W_in,  const float* __restrict__ b_in,
    const float* __restrict__ W_flr, const float* __restrict__ b_flr,
    const float* __restrict__ W_s,   const float* __restrict__ b_s,
    const float* __restrict__ W_out, const float* __restrict__ b_out,
    const float* __restrict__ bn_g,  const float* __restrict__ bn_b,
    const float* __restrict__ bn_m,  const float* __restrict__ bn_v,
    const float* __restrict__ W_o0,  const float* __restrict__ b_o0,
    const float* __restrict__ W_o1,  const float* __restrict__ b_o1,
    float* __restrict__ out)
{
  const int b    = blockIdx.x;
  const int t    = threadIdx.x;
  const int lane = t & 63;
  const int wave = t >> 6;

  // feat rows padded to 32 floats (128B) with XOR granule swizzle -> conflict-free
  __shared__ float sFeat[VV][32];        // 128 KB
  __shared__ float sAgg[NAGG][48];
  __shared__ float sM[NAGG][NFILT];
  __shared__ float sRed[8][FIN];
  __shared__ float sMean[FIN];

  // ---------- phase 0: load x, per-event mean over V ----------
  float xv[2][FIN];
  #pragma unroll
  for (int vi = 0; vi < 2; ++vi){
    const float* xp = x + ((size_t)b * VV + (t + vi * TPB)) * FIN;
    #pragma unroll
    for (int c = 0; c < FIN; ++c) xv[vi][c] = xp[c];
  }
  {
    float ps[FIN];
    #pragma unroll
    for (int c = 0; c < FIN; ++c) ps[c] = xv[0][c] + xv[1][c];
    #pragma unroll
    for (int m = 32; m > 0; m >>= 1){
      #pragma unroll
      for (int c = 0; c < FIN; ++c) ps[c] += __shfl_xor(ps[c], m, 64);
    }
    if (lane == 0){
      #pragma unroll
      for (int c = 0; c < FIN; ++c) sRed[wave][c] = ps[c];
    }
  }
  __syncthreads();
  if (t < FIN){
    float s = 0.f;
    #pragma unroll
    for (int wv = 0; wv < 8; ++wv) s += sRed[wv][t];
    sMean[t] = s * (1.0f / VV);
  }
  __syncthreads();

  // ---------- input dense: h = tanh(bn0(concat(x,mean)) @ W_in + b_in) ----------
  float h0[NFILT], h1[NFILT];
  {
    float hm[NFILT];
    #pragma unroll
    for (int j = 0; j < NFILT; ++j) hm[j] = b_in[j];
    #pragma unroll
    for (int c = 0; c < FIN; ++c){
      float z = (sMean[c] - bn0_m[FIN+c]) * (bn0_g[FIN+c] * rsqrtf(bn0_v[FIN+c] + BN_EPS)) + bn0_b[FIN+c];
      #pragma unroll
      for (int j = 0; j < NFILT; ++j) hm[j] += z * W_in[(FIN+c)*NFILT + j];
    }
    #pragma unroll
    for (int vi = 0; vi < 2; ++vi){
      float o[NFILT];
      #pragma unroll
      for (int j = 0; j < NFILT; ++j) o[j] = hm[j];
      #pragma unroll
      for (int c = 0; c < FIN; ++c){
        float z = (xv[vi][c] - bn0_m[c]) * (bn0_g[c] * rsqrtf(bn0_v[c] + BN_EPS)) + bn0_b[c];
        #pragma unroll
        for (int j = 0; j < NFILT; ++j) o[j] += z * W_in[c*NFILT + j];
      }
      float* h = vi ? h1 : h0;
      #pragma unroll
      for (int j = 0; j < NFILT; ++j) h[j] = fast_tanh(o[j]);
    }
  }

  // fused final-layer accumulator: acc48 = b_o0 + sum_l out_l @ W_o0[l*32:(l+1)*32,:]
  float acc0[48], acc1[48];
  #pragma unroll
  for (int n = 0; n < 48; ++n){ acc0[n] = b_o0[n]; acc1[n] = b_o0[n]; }

  float w0a[NAGG], w1a[NAGG];

  for (int l = 0; l < NBLK; ++l){
    const float* Wf = W_flr + l * NFILT * NPROP;
    const float* bf = b_flr + l * NPROP;
    const float* Ws = W_s   + l * NFILT * NAGG;
    const float* bs = b_s   + l * NAGG;
    const float* Wo = W_out + l * 228 * NFILT;
    const float* bo = b_out + l * NFILT;
    const float* g_ = bn_g  + l * NFILT;
    const float* be = bn_b  + l * NFILT;
    const float* bm = bn_m  + l * NFILT;
    const float* bv = bn_v  + l * NFILT;

    // ---- stage 1: f = h@Wf+bf, d = h@Ws+bs, w = exp(-|d|); stage feat to LDS ----
    #pragma unroll
    for (int vi = 0; vi < 2; ++vi){
      const float* h  = vi ? h1  : h0;
      float*       wv = vi ? w1a : w0a;
      const int v  = t + vi * TPB;
      const int sw = v & 7;
      float f[NPROP];
      #pragma unroll
      for (int p = 0; p < NPROP; ++p) f[p] = bf[p];
      float d[NAGG];
      #pragma unroll
      for (int a = 0; a < NAGG; ++a) d[a] = bs[a];
      #pragma unroll
      for (int k = 0; k < NFILT; ++k){
        const float hk = h[k];
        #pragma unroll
        for (int p = 0; p < NPROP; ++p) f[p] += hk * Wf[k*NPROP + p];
        #pragma unroll
        for (int a = 0; a < NAGG; ++a)  d[a] += hk * Ws[k*NAGG + a];
      }
      #pragma unroll
      for (int a = 0; a < NAGG; ++a) wv[a] = __expf(-fabsf(d[a]));
      #pragma unroll
      for (int q = 0; q < 5; ++q){
        *(float4*)&sFeat[v][((q ^ sw) << 2)] =
            make_float4(f[4*q], f[4*q+1], f[4*q+2], f[4*q+3]);
      }
      *(float4*)&sFeat[v][((5 ^ sw) << 2)] = make_float4(wv[0], wv[1], wv[2], wv[3]);
    }
    __syncthreads();

    // ---- stage 2: 96 sums + 96 maxes over V; wave g owns c-quad g (g<6) ----
    {
      const int g = wave;
      if (g < 6){
        float psum[NAGG][4], pmax[NAGG][4];
        #pragma unroll
        for (int a = 0; a < NAGG; ++a)
          #pragma unroll
          for (int c = 0; c < 4; ++c){ psum[a][c] = 0.f; pmax[a][c] = -INFINITY; }
        for (int i = 0; i < 16; ++i){
          const int v  = i * 64 + lane;
          const int sw = v & 7;
          const float4 fq = *(const float4*)&sFeat[v][((g ^ sw) << 2)];
          const float4 wq = *(const float4*)&sFeat[v][((5 ^ sw) << 2)];
          const float fc[4] = {fq.x, fq.y, fq.z, fq.w};
          const float wa[4] = {wq.x, wq.y, wq.z, wq.w};
          #pragma unroll
          for (int a = 0; a < NAGG; ++a)
            #pragma unroll
            for (int c = 0; c < 4; ++c){
              const float p = wa[a] * fc[c];
              psum[a][c] += p;
              pmax[a][c]  = fmaxf(pmax[a][c], p);
            }
        }
        #pragma unroll
        for (int m = 32; m > 0; m >>= 1){
          #pragma unroll
          for (int a = 0; a < NAGG; ++a)
            #pragma unroll
            for (int c = 0; c < 4; ++c){
              psum[a][c] += __shfl_xor(psum[a][c], m, 64);
              pmax[a][c]  = fmaxf(pmax[a][c], __shfl_xor(pmax[a][c], m, 64));
            }
        }
        if (lane == 0){
          #pragma unroll
          for (int a = 0; a < NAGG; ++a)
            #pragma unroll
            for (int c = 0; c < 4; ++c){
              sAgg[a][g*4 + c]      = pmax[a][c];
              sAgg[a][24 + g*4 + c] = psum[a][c] * (1.0f / VV);
            }
        }
      }
    }
    __syncthreads();

    // ---- M'[a][j] = sum_c agg[a][c]*Wo[32+a*48+c][j] + Wo[224+a][j] ----
    if (t < 128){
      const int a = t >> 5, j = t & 31;
      float m = Wo[(224 + a) * NFILT + j];
      #pragma unroll 8
      for (int c = 0; c < 48; ++c) m += sAgg[a][c] * Wo[(32 + a*48 + c) * NFILT + j];
      sM[a][j] = m;
    }
    __syncthreads();

    // ---- stage 3: out_j = bn(tanh(h@WoH + w@M' + bo)); acc48 += out@Wo0_slice ----
    #pragma unroll
    for (int q = 0; q < 8; ++q){
      const float4 m0 = *(const float4*)&sM[0][q*4];
      const float4 m1 = *(const float4*)&sM[1][q*4];
      const float4 m2 = *(const float4*)&sM[2][q*4];
      const float4 m3 = *(const float4*)&sM[3][q*4];
      const float mq[NAGG][4] = {
        {m0.x, m0.y, m0.z, m0.w},
        {m1.x, m1.y, m1.z, m1.w},
        {m2.x, m2.y, m2.z, m2.w},
        {m3.x, m3.y, m3.z, m3.w}};
      #pragma unroll
      for (int vi = 0; vi < 2; ++vi){
        const float* h   = vi ? h1  : h0;
        const float* wv  = vi ? w1a : w0a;
        float*       acc = vi ? acc1 : acc0;
        const int v  = t + vi * TPB;
        const int sw = v & 7;
        float val[4];
        #pragma unroll
        for (int jj = 0; jj < 4; ++jj){
          const int j = q*4 + jj;
          float o = bo[j] + wv[0]*mq[0][jj] + wv[1]*mq[1][jj]
                          + wv[2]*mq[2][jj] + wv[3]*mq[3][jj];
          #pragma unroll
          for (int k = 0; k < NFILT; ++k) o += h[k] * Wo[k*NFILT + j];
          const float th = fast_tanh(o);
          val[jj] = (th - bm[j]) * (g_[j] * rsqrtf(bv[j] + BN_EPS)) + be[j];
        }
        #pragma unroll
        for (int jj = 0; jj < 4; ++jj){
          const int j = q*4 + jj;
          const float* wrow = W_o0 + ((size_t)(l*NFILT + j)) * 48;
          #pragma unroll
          for (int n = 0; n < 48; ++n) acc[n] += val[jj] * wrow[n];
        }
        *(float4*)&sFeat[v][((q ^ sw) << 2)] = make_float4(val[0], val[1], val[2], val[3]);
      }
    }
    // read back new h (same thread wrote its own rows; no barrier needed)
    #pragma unroll
    for (int vi = 0; vi < 2; ++vi){
      float* h = vi ? h1 : h0;
      const int v  = t + vi * TPB;
      const int sw = v & 7;
      #pragma unroll
      for (int q = 0; q < 8; ++q){
        const float4 hv = *(const float4*)&sFeat[v][((q ^ sw) << 2)];
        h[4*q+0] = hv.x; h[4*q+1] = hv.y; h[4*q+2] = hv.z; h[4*q+3] = hv.w;
      }
    }
  }

  // ---------- head: relu(acc48) @ W_o1 + b_o1, relu ----------
  #pragma unroll
  for (int vi = 0; vi < 2; ++vi){
    const float* acc = vi ? acc1 : acc0;
    const int v = t + vi * TPB;
    float o3[3] = {b_o1[0], b_o1[1], b_o1[2]};
    #pragma unroll
    for (int n = 0; n < 48; ++n){
      const float hn = fmaxf(acc[n], 0.f);
      o3[0] += hn * W_o1[n*3 + 0];
      o3[1] += hn * W_o1[n*3 + 1];
      o3[2] += hn * W_o1[n*3 + 2];
    }
    float* op = out + ((size_t)b * VV + v) * 3;
    op[0] = fmaxf(o3[0], 0.f);
    op[1] = fmaxf(o3[1], 0.f);
    op[2] = fmaxf(o3[2], 0.f);
  }
}

extern "C" void kernel_launch(void* const* d_in, const int* in_sizes, int n_in,
                              void* d_out, int out_size, void* d_ws, size_t ws_size,
                              hipStream_t stream) {
  const float* x      = (const float*)d_in[0];
  const float* bn0_g  = (const float*)d_in[1];
  const float* bn0_b  = (const float*)d_in[2];
  const float* bn0_m  = (const float*)d_in[3];
  const float* bn0_v  = (const float*)d_in[4];
  const float* W_in   = (const float*)d_in[5];
  const float* b_in   = (const float*)d_in[6];
  const float* W_flr  = (const float*)d_in[7];
  const float* b_flr  = (const float*)d_in[8];
  const float* W_s    = (const float*)d_in[9];
  const float* b_s    = (const float*)d_in[10];
  const float* W_out  = (const float*)d_in[11];
  const float* b_out  = (const float*)d_in[12];
  const float* bn_g   = (const float*)d_in[13];
  const float* bn_b   = (const float*)d_in[14];
  const float* bn_m   = (const float*)d_in[15];
  const float* bn_v   = (const float*)d_in[16];
  const float* W_o0   = (const float*)d_in[17];
  const float* b_o0   = (const float*)d_in[18];
  const float* W_o1   = (const float*)d_in[19];
  const float* b_o1   = (const float*)d_in[20];

  garnet_fused<<<dim3(BB), dim3(TPB), 0, stream>>>(
      x, bn0_g, bn0_b, bn0_m, bn0_v, W_in, b_in,
      W_flr, b_flr, W_s, b_s, W_out, b_out,
      bn_g, bn_b, bn_m, bn_v, W_o0, b_o0, W_o1, b_o1,
      (float*)d_out);
}

// Round 2
// 1296.945 us; speedup vs baseline: 1.0022x; 1.0022x over previous
//
#include <hip/hip_runtime.h>
#include <math.h>

#define NBLK  11
#define NAGG  4
#define NFILT 32
#define NPROP 20
#define BB    128
#define VV    1024
#define FIN   10
#define TPB   512
#define BN_EPS 1e-3f

__device__ __forceinline__ float fast_tanh(float x){
  float a = fabsf(x);
  float e = __expf(-2.0f * a);
  float r = (1.0f - e) / (1.0f + e);
  return copysignf(r, x);
}

// LDS = 133 KB -> only 1 WG/CU fits no matter what; allow the full 256-VGPR
// budget (min-waves-per-EU = 1) so the ~200-reg live set never spills.
__global__ __launch_bounds__(TPB, 1) void garnet_fused(
    const float* __restrict__ x,
    const float* __restrict__ bn0_g, const float* __restrict__ bn0_b,
    const float* __restrict__ bn0_m, const float* __restrict__ bn0_v,
    const float* __restrict__ W_in,  const float* __restrict__ b_in,
    const float* __restrict__ W_flr, const float* __restrict__ b_flr,
    const float* __restrict__ W_s,   const float* __restrict__ b_s,
    const float* __restrict__ W_out, const float* __restrict__ b_out,
    const float* __restrict__ bn_g,  const float* __restrict__ bn_b,
    const float* __restrict__ bn_m,  const float* __restrict__ bn_v,
    const float* __restrict__ W_o0,  const float* __restrict__ b_o0,
    const float* __restrict__ W_o1,  const float* __restrict__ b_o1,
    float* __restrict__ out)
{
  const int b    = blockIdx.x;
  const int t    = threadIdx.x;
  const int lane = t & 63;
  const int wave = t >> 6;

  // feat rows padded to 32 floats (128B) with XOR granule swizzle -> conflict-free
  __shared__ float sFeat[VV][32];        // 128 KB
  __shared__ float sAgg[NAGG][48];
  __shared__ float sM[NAGG][NFILT];
  __shared__ float sRed[8][FIN];
  __shared__ float sMean[FIN];

  float h0[NFILT], h1[NFILT];

  // ---------- phase 0 + input dense (prologue regs scoped so they die) ----------
  {
    float xv[2][FIN];
    #pragma unroll
    for (int vi = 0; vi < 2; ++vi){
      const float* xp = x + ((size_t)b * VV + (t + vi * TPB)) * FIN;
      #pragma unroll
      for (int c = 0; c < FIN; ++c) xv[vi][c] = xp[c];
    }
    {
      float ps[FIN];
      #pragma unroll
      for (int c = 0; c < FIN; ++c) ps[c] = xv[0][c] + xv[1][c];
      #pragma unroll
      for (int m = 32; m > 0; m >>= 1){
        #pragma unroll
        for (int c = 0; c < FIN; ++c) ps[c] += __shfl_xor(ps[c], m, 64);
      }
      if (lane == 0){
        #pragma unroll
        for (int c = 0; c < FIN; ++c) sRed[wave][c] = ps[c];
      }
    }
    __syncthreads();
    if (t < FIN){
      float s = 0.f;
      #pragma unroll
      for (int wv = 0; wv < 8; ++wv) s += sRed[wv][t];
      sMean[t] = s * (1.0f / VV);
    }
    __syncthreads();

    // h = tanh(bn0(concat(x,mean)) @ W_in + b_in)
    float hm[NFILT];
    #pragma unroll
    for (int j = 0; j < NFILT; ++j) hm[j] = b_in[j];
    #pragma unroll
    for (int c = 0; c < FIN; ++c){
      float z = (sMean[c] - bn0_m[FIN+c]) * (bn0_g[FIN+c] * rsqrtf(bn0_v[FIN+c] + BN_EPS)) + bn0_b[FIN+c];
      #pragma unroll
      for (int j = 0; j < NFILT; ++j) hm[j] += z * W_in[(FIN+c)*NFILT + j];
    }
    #pragma unroll
    for (int vi = 0; vi < 2; ++vi){
      float o[NFILT];
      #pragma unroll
      for (int j = 0; j < NFILT; ++j) o[j] = hm[j];
      #pragma unroll
      for (int c = 0; c < FIN; ++c){
        float z = (xv[vi][c] - bn0_m[c]) * (bn0_g[c] * rsqrtf(bn0_v[c] + BN_EPS)) + bn0_b[c];
        #pragma unroll
        for (int j = 0; j < NFILT; ++j) o[j] += z * W_in[c*NFILT + j];
      }
      float* h = vi ? h1 : h0;
      #pragma unroll
      for (int j = 0; j < NFILT; ++j) h[j] = fast_tanh(o[j]);
    }
  }

  // fused final-layer accumulator: acc48 = b_o0 + sum_l out_l @ W_o0[l*32:(l+1)*32,:]
  float acc0[48], acc1[48];
  #pragma unroll
  for (int n = 0; n < 48; ++n){ acc0[n] = b_o0[n]; acc1[n] = b_o0[n]; }

  float w0a[NAGG], w1a[NAGG];

  for (int l = 0; l < NBLK; ++l){
    const float* Wf = W_flr + l * NFILT * NPROP;
    const float* bf = b_flr + l * NPROP;
    const float* Ws = W_s   + l * NFILT * NAGG;
    const float* bs = b_s   + l * NAGG;
    const float* Wo = W_out + l * 228 * NFILT;
    const float* bo = b_out + l * NFILT;
    const float* g_ = bn_g  + l * NFILT;
    const float* be = bn_b  + l * NFILT;
    const float* bm = bn_m  + l * NFILT;
    const float* bv = bn_v  + l * NFILT;

    // ---- stage 1: f = h@Wf+bf, d = h@Ws+bs, w = exp(-|d|); stage feat to LDS ----
    #pragma unroll
    for (int vi = 0; vi < 2; ++vi){
      const float* h  = vi ? h1  : h0;
      float*       wv = vi ? w1a : w0a;
      const int v  = t + vi * TPB;
      const int sw = v & 7;
      float f[NPROP];
      #pragma unroll
      for (int p = 0; p < NPROP; ++p) f[p] = bf[p];
      float d[NAGG];
      #pragma unroll
      for (int a = 0; a < NAGG; ++a) d[a] = bs[a];
      #pragma unroll
      for (int k = 0; k < NFILT; ++k){
        const float hk = h[k];
        #pragma unroll
        for (int p = 0; p < NPROP; ++p) f[p] += hk * Wf[k*NPROP + p];
        #pragma unroll
        for (int a = 0; a < NAGG; ++a)  d[a] += hk * Ws[k*NAGG + a];
      }
      #pragma unroll
      for (int a = 0; a < NAGG; ++a) wv[a] = __expf(-fabsf(d[a]));
      #pragma unroll
      for (int q = 0; q < 5; ++q){
        *(float4*)&sFeat[v][((q ^ sw) << 2)] =
            make_float4(f[4*q], f[4*q+1], f[4*q+2], f[4*q+3]);
      }
      *(float4*)&sFeat[v][((5 ^ sw) << 2)] = make_float4(wv[0], wv[1], wv[2], wv[3]);
    }
    __syncthreads();

    // ---- stage 2: 96 sums + 96 maxes over V; wave g owns c-quad g (g<6) ----
    {
      const int g = wave;
      if (g < 6){
        float psum[NAGG][4], pmax[NAGG][4];
        #pragma unroll
        for (int a = 0; a < NAGG; ++a)
          #pragma unroll
          for (int c = 0; c < 4; ++c){ psum[a][c] = 0.f; pmax[a][c] = -INFINITY; }
        for (int i = 0; i < 16; ++i){
          const int v  = i * 64 + lane;
          const int sw = v & 7;
          const float4 fq = *(const float4*)&sFeat[v][((g ^ sw) << 2)];
          const float4 wq = *(const float4*)&sFeat[v][((5 ^ sw) << 2)];
          const float fc[4] = {fq.x, fq.y, fq.z, fq.w};
          const float wa[4] = {wq.x, wq.y, wq.z, wq.w};
          #pragma unroll
          for (int a = 0; a < NAGG; ++a)
            #pragma unroll
            for (int c = 0; c < 4; ++c){
              const float p = wa[a] * fc[c];
              psum[a][c] += p;
              pmax[a][c]  = fmaxf(pmax[a][c], p);
            }
        }
        #pragma unroll
        for (int m = 32; m > 0; m >>= 1){
          #pragma unroll
          for (int a = 0; a < NAGG; ++a)
            #pragma unroll
            for (int c = 0; c < 4; ++c){
              psum[a][c] += __shfl_xor(psum[a][c], m, 64);
              pmax[a][c]  = fmaxf(pmax[a][c], __shfl_xor(pmax[a][c], m, 64));
            }
        }
        if (lane == 0){
          #pragma unroll
          for (int a = 0; a < NAGG; ++a)
            #pragma unroll
            for (int c = 0; c < 4; ++c){
              sAgg[a][g*4 + c]      = pmax[a][c];
              sAgg[a][24 + g*4 + c] = psum[a][c] * (1.0f / VV);
            }
        }
      }
    }
    __syncthreads();

    // ---- M'[a][j] = sum_c agg[a][c]*Wo[32+a*48+c][j] + Wo[224+a][j] ----
    if (t < 128){
      const int a = t >> 5, j = t & 31;
      float m = Wo[(224 + a) * NFILT + j];
      #pragma unroll 8
      for (int c = 0; c < 48; ++c) m += sAgg[a][c] * Wo[(32 + a*48 + c) * NFILT + j];
      sM[a][j] = m;
    }
    __syncthreads();

    // ---- stage 3: out_j = bn(tanh(h@WoH + w@M' + bo)); acc48 += out@Wo0_slice ----
    #pragma unroll
    for (int q = 0; q < 8; ++q){
      const float4 m0 = *(const float4*)&sM[0][q*4];
      const float4 m1 = *(const float4*)&sM[1][q*4];
      const float4 m2 = *(const float4*)&sM[2][q*4];
      const float4 m3 = *(const float4*)&sM[3][q*4];
      const float mq[NAGG][4] = {
        {m0.x, m0.y, m0.z, m0.w},
        {m1.x, m1.y, m1.z, m1.w},
        {m2.x, m2.y, m2.z, m2.w},
        {m3.x, m3.y, m3.z, m3.w}};
      #pragma unroll
      for (int vi = 0; vi < 2; ++vi){
        const float* h   = vi ? h1  : h0;
        const float* wv  = vi ? w1a : w0a;
        float*       acc = vi ? acc1 : acc0;
        const int v  = t + vi * TPB;
        const int sw = v & 7;
        float val[4];
        #pragma unroll
        for (int jj = 0; jj < 4; ++jj){
          const int j = q*4 + jj;
          float o = bo[j] + wv[0]*mq[0][jj] + wv[1]*mq[1][jj]
                          + wv[2]*mq[2][jj] + wv[3]*mq[3][jj];
          #pragma unroll
          for (int k = 0; k < NFILT; ++k) o += h[k] * Wo[k*NFILT + j];
          const float th = fast_tanh(o);
          val[jj] = (th - bm[j]) * (g_[j] * rsqrtf(bv[j] + BN_EPS)) + be[j];
        }
        #pragma unroll
        for (int jj = 0; jj < 4; ++jj){
          const int j = q*4 + jj;
          const float* wrow = W_o0 + ((size_t)(l*NFILT + j)) * 48;
          #pragma unroll
          for (int n = 0; n < 48; ++n) acc[n] += val[jj] * wrow[n];
        }
        *(float4*)&sFeat[v][((q ^ sw) << 2)] = make_float4(val[0], val[1], val[2], val[3]);
      }
    }
    // read back new h (same thread wrote its own rows; no barrier needed)
    #pragma unroll
    for (int vi = 0; vi < 2; ++vi){
      float* h = vi ? h1 : h0;
      const int v  = t + vi * TPB;
      const int sw = v & 7;
      #pragma unroll
      for (int q = 0; q < 8; ++q){
        const float4 hv = *(const float4*)&sFeat[v][((q ^ sw) << 2)];
        h[4*q+0] = hv.x; h[4*q+1] = hv.y; h[4*q+2] = hv.z; h[4*q+3] = hv.w;
      }
    }
  }

  // ---------- head: relu(acc48) @ W_o1 + b_o1, relu ----------
  #pragma unroll
  for (int vi = 0; vi < 2; ++vi){
    const float* acc = vi ? acc1 : acc0;
    const int v = t + vi * TPB;
    float o3[3] = {b_o1[0], b_o1[1], b_o1[2]};
    #pragma unroll
    for (int n = 0; n < 48; ++n){
      const float hn = fmaxf(acc[n], 0.f);
      o3[0] += hn * W_o1[n*3 + 0];
      o3[1] += hn * W_o1[n*3 + 1];
      o3[2] += hn * W_o1[n*3 + 2];
    }
    float* op = out + ((size_t)b * VV + v) * 3;
    op[0] = fmaxf(o3[0], 0.f);
    op[1] = fmaxf(o3[1], 0.f);
    op[2] = fmaxf(o3[2], 0.f);
  }
}

extern "C" void kernel_launch(void* const* d_in, const int* in_sizes, int n_in,
                              void* d_out, int out_size, void* d_ws, size_t ws_size,
                              hipStream_t stream) {
  const float* x      = (const float*)d_in[0];
  const float* bn0_g  = (const float*)d_in[1];
  const float* bn0_b  = (const float*)d_in[2];
  const float* bn0_m  = (const float*)d_in[3];
  const float* bn0_v  = (const float*)d_in[4];
  const float* W_in   = (const float*)d_in[5];
  const float* b_in   = (const float*)d_in[6];
  const float* W_flr  = (const float*)d_in[7];
  const float* b_flr  = (const float*)d_in[8];
  const float* W_s    = (const float*)d_in[9];
  const float* b_s    = (const float*)d_in[10];
  const float* W_out  = (const float*)d_in[11];
  const float* b_out  = (const float*)d_in[12];
  const float* bn_g   = (const float*)d_in[13];
  const float* bn_b   = (const float*)d_in[14];
  const float* bn_m   = (const float*)d_in[15];
  const float* bn_v   = (const float*)d_in[16];
  const float* W_o0   = (const float*)d_in[17];
  const float* b_o0   = (const float*)d_in[18];
  const float* W_o1   = (const float*)d_in[19];
  const float* b_o1   = (const float*)d_in[20];

  garnet_fused<<<dim3(BB), dim3(TPB), 0, stream>>>(
      x, bn0_g, bn0_b, bn0_m, bn0_v, W_in, b_in,
      W_flr, b_flr, W_s, b_s, W_out, b_out,
      bn_g, bn_b, bn_m, bn_v, W_o0, b_o0, W_o1, b_o1,
      (float*)d_out);
}

// Round 3
// 946.747 us; speedup vs baseline: 1.3730x; 1.3699x over previous
//
#include <hip/hip_runtime.h>
#include <math.h>

#define NBLK  11
#define NAGG  4
#define NFILT 32
#define NPROP 20
#define BB    128
#define VV    1024
#define HV    512
#define FIN   10
#define TPB   512
#define BN_EPS 1e-3f

// d_ws layout: [0..127] int flags (memset 0 per launch);
// floats: mean partials at [128 .. 128+128*2*10), agg partials after.
#define WSF_MEAN 128
#define WSF_AGG  (WSF_MEAN + BB*2*FIN)

__device__ __forceinline__ float fast_tanh(float x){
  float a = fabsf(x);
  float e = __expf(-2.0f * a);
  float r = (1.0f - e) / (1.0f + e);
  return copysignf(r, x);
}

// pairwise event sync: each WG posts once, waits until both posted.
__device__ __forceinline__ void pair_sync(int* flag, int target){
  __syncthreads();
  if (threadIdx.x == 0){
    __threadfence();
    __hip_atomic_fetch_add(flag, 1, __ATOMIC_RELEASE, __HIP_MEMORY_SCOPE_AGENT);
    while (__hip_atomic_load(flag, __ATOMIC_ACQUIRE, __HIP_MEMORY_SCOPE_AGENT) < target)
      __builtin_amdgcn_s_sleep(2);
  }
  __syncthreads();
}

extern "C" __global__ __launch_bounds__(TPB) void garnet_fused(
    const float* __restrict__ x,
    const float* __restrict__ bn0_g, const float* __restrict__ bn0_b,
    const float* __restrict__ bn0_m, const float* __restrict__ bn0_v,
    const float* __restrict__ W_in,  const float* __restrict__ b_in,
    const float* __restrict__ W_flr, const float* __restrict__ b_flr,
    const float* __restrict__ W_s,   const float* __restrict__ b_s,
    const float* __restrict__ W_out, const float* __restrict__ b_out,
    const float* __restrict__ bn_g,  const float* __restrict__ bn_b,
    const float* __restrict__ bn_m,  const float* __restrict__ bn_v,
    const float* __restrict__ W_o0,  const float* __restrict__ b_o0,
    const float* __restrict__ W_o1,  const float* __restrict__ b_o1,
    int* __restrict__ wsFlag, float* __restrict__ wsF,
    float* __restrict__ out)
{
  const int wg   = blockIdx.x;
  const int b    = wg & (BB - 1);     // partner wg = wg^128 -> same XCD (wg%8 equal)
  const int half = wg >> 7;
  const int t    = threadIdx.x;
  const int lane = t & 63;
  const int wave = t >> 6;
  const int v    = half * HV + t;     // global vertex this thread owns
  const int sw   = t & 7;             // LDS granule swizzle for own row

  __shared__ float sFeat[HV][32];     // 64 KB, rows 128B, XOR-swizzled granules
  __shared__ float sAgg[NAGG][48];
  __shared__ float sM[NAGG][NFILT];
  __shared__ float sRed[8][FIN];
  __shared__ float sMean[FIN];

  int* flag = wsFlag + b;

  // ---------------- phase 0: mean over V (cross-half) + input dense ----------------
  float h[NFILT];
  {
    float xv[FIN];
    const float* xp = x + ((size_t)b * VV + v) * FIN;
    #pragma unroll
    for (int c = 0; c < FIN; ++c) xv[c] = xp[c];

    float ps[FIN];
    #pragma unroll
    for (int c = 0; c < FIN; ++c) ps[c] = xv[c];
    #pragma unroll
    for (int m = 32; m > 0; m >>= 1){
      #pragma unroll
      for (int c = 0; c < FIN; ++c) ps[c] += __shfl_xor(ps[c], m, 64);
    }
    if (lane == 0){
      #pragma unroll
      for (int c = 0; c < FIN; ++c) sRed[wave][c] = ps[c];
    }
    __syncthreads();
    if (t < FIN){
      float s = 0.f;
      #pragma unroll
      for (int wv = 0; wv < 8; ++wv) s += sRed[wv][t];
      sRed[0][t] = s;                                   // my half-partial
      __hip_atomic_store(&wsF[WSF_MEAN + (b*2 + half)*FIN + t], s,
                         __ATOMIC_RELAXED, __HIP_MEMORY_SCOPE_AGENT);
      __threadfence();
    }
    pair_sync(flag, 2);
    if (t < FIN){
      float theirs = __hip_atomic_load(&wsF[WSF_MEAN + (b*2 + (half^1))*FIN + t],
                                       __ATOMIC_RELAXED, __HIP_MEMORY_SCOPE_AGENT);
      sMean[t] = (sRed[0][t] + theirs) * (1.0f / VV);
    }
    __syncthreads();

    // h = tanh(bn0(concat(x,mean)) @ W_in + b_in)
    float o[NFILT];
    #pragma unroll
    for (int j = 0; j < NFILT; ++j) o[j] = b_in[j];
    #pragma unroll
    for (int c = 0; c < FIN; ++c){
      const float zx = (xv[c]    - bn0_m[c])     * (bn0_g[c]     * rsqrtf(bn0_v[c]     + BN_EPS)) + bn0_b[c];
      const float zm = (sMean[c] - bn0_m[FIN+c]) * (bn0_g[FIN+c] * rsqrtf(bn0_v[FIN+c] + BN_EPS)) + bn0_b[FIN+c];
      #pragma unroll
      for (int j = 0; j < NFILT; ++j)
        o[j] += zx * W_in[c*NFILT + j] + zm * W_in[(FIN+c)*NFILT + j];
    }
    #pragma unroll
    for (int j = 0; j < NFILT; ++j) h[j] = fast_tanh(o[j]);
  }

  // fused head accumulator: acc48 = b_o0 + sum_l out_l @ W_o0[l*32:(l+1)*32,:]
  float acc[48];
  #pragma unroll
  for (int n = 0; n < 48; ++n) acc[n] = b_o0[n];

  float w[NAGG];

  for (int l = 0; l < NBLK; ++l){
    const float* Wf = W_flr + l * NFILT * NPROP;
    const float* bf = b_flr + l * NPROP;
    const float* Ws = W_s   + l * NFILT * NAGG;
    const float* bs = b_s   + l * NAGG;
    const float* Wo = W_out + l * 228 * NFILT;
    const float* bo = b_out + l * NFILT;
    const float* g_ = bn_g  + l * NFILT;
    const float* be = bn_b  + l * NFILT;
    const float* bm = bn_m  + l * NFILT;
    const float* bv = bn_v  + l * NFILT;

    // ---- stage 1: f = h@Wf+bf, d = h@Ws+bs, w = exp(-|d|); feat -> LDS ----
    {
      float f[NPROP];
      #pragma unroll
      for (int p = 0; p < NPROP; ++p) f[p] = bf[p];
      float d[NAGG];
      #pragma unroll
      for (int a = 0; a < NAGG; ++a) d[a] = bs[a];
      #pragma unroll
      for (int k = 0; k < NFILT; ++k){
        const float hk = h[k];
        #pragma unroll
        for (int p = 0; p < NPROP; ++p) f[p] += hk * Wf[k*NPROP + p];
        #pragma unroll
        for (int a = 0; a < NAGG; ++a)  d[a] += hk * Ws[k*NAGG + a];
      }
      #pragma unroll
      for (int a = 0; a < NAGG; ++a) w[a] = __expf(-fabsf(d[a]));
      #pragma unroll
      for (int q = 0; q < 5; ++q)
        *(float4*)&sFeat[t][((q ^ sw) << 2)] = make_float4(f[4*q], f[4*q+1], f[4*q+2], f[4*q+3]);
      *(float4*)&sFeat[t][((5 ^ sw) << 2)] = make_float4(w[0], w[1], w[2], w[3]);
    }
    __syncthreads();

    // ---- stage 2: partial max/sum over this half's 512 rows; wave g owns c-quad g ----
    if (wave < 6){
      const int g = wave;
      float psum[NAGG][4], pmax[NAGG][4];
      #pragma unroll
      for (int a = 0; a < NAGG; ++a)
        #pragma unroll
        for (int c = 0; c < 4; ++c){ psum[a][c] = 0.f; pmax[a][c] = -INFINITY; }
      #pragma unroll 2
      for (int i = 0; i < 8; ++i){
        const int row = i * 64 + lane;
        const int rs  = row & 7;
        const float4 fq = *(const float4*)&sFeat[row][((g ^ rs) << 2)];
        const float4 wq = *(const float4*)&sFeat[row][((5 ^ rs) << 2)];
        const float fc[4] = {fq.x, fq.y, fq.z, fq.w};
        const float wa[4] = {wq.x, wq.y, wq.z, wq.w};
        #pragma unroll
        for (int a = 0; a < NAGG; ++a)
          #pragma unroll
          for (int c = 0; c < 4; ++c){
            const float p = wa[a] * fc[c];
            psum[a][c] += p;
            pmax[a][c]  = fmaxf(pmax[a][c], p);
          }
      }
      #pragma unroll
      for (int m = 32; m > 0; m >>= 1){
        #pragma unroll
        for (int a = 0; a < NAGG; ++a)
          #pragma unroll
          for (int c = 0; c < 4; ++c){
            psum[a][c] += __shfl_xor(psum[a][c], m, 64);
            pmax[a][c]  = fmaxf(pmax[a][c], __shfl_xor(pmax[a][c], m, 64));
          }
      }
      if (lane == 0){
        float* gp = wsF + WSF_AGG + (((size_t)(b*2 + (l&1))*2 + half) * NAGG * 48);
        #pragma unroll
        for (int a = 0; a < NAGG; ++a)
          #pragma unroll
          for (int c = 0; c < 4; ++c){
            sAgg[a][g*4 + c]      = pmax[a][c];          // raw partial max
            sAgg[a][24 + g*4 + c] = psum[a][c];          // raw partial sum
            __hip_atomic_store(&gp[a*48 + g*4 + c],      pmax[a][c], __ATOMIC_RELAXED, __HIP_MEMORY_SCOPE_AGENT);
            __hip_atomic_store(&gp[a*48 + 24 + g*4 + c], psum[a][c], __ATOMIC_RELAXED, __HIP_MEMORY_SCOPE_AGENT);
          }
        __threadfence();
      }
    }
    pair_sync(flag, 2*l + 4);

    // ---- combine halves: max of maxes, mean = (sum0+sum1)/V ----
    if (t < 192){
      const int a = t / 48, c = t - a * 48;
      const float* pp = wsF + WSF_AGG + (((size_t)(b*2 + (l&1))*2 + (half^1)) * NAGG * 48);
      const float mine   = sAgg[a][c];
      const float theirs = __hip_atomic_load(&pp[a*48 + c], __ATOMIC_RELAXED, __HIP_MEMORY_SCOPE_AGENT);
      sAgg[a][c] = (c < 24) ? fmaxf(mine, theirs) : (mine + theirs) * (1.0f / VV);
    }
    __syncthreads();

    // ---- M'[a][j] = sum_c agg[a][c]*Wo[32+a*48+c][j] + Wo[224+a][j] ----
    if (t < 128){
      const int a = t >> 5, j = t & 31;
      float m = Wo[(224 + a) * NFILT + j];
      #pragma unroll 8
      for (int c = 0; c < 48; ++c) m += sAgg[a][c] * Wo[(32 + a*48 + c) * NFILT + j];
      sM[a][j] = m;
    }
    __syncthreads();

    // ---- stage 3: out_j = bn(tanh(h@WoH + w@M' + bo)); acc += out@Wo0_slice ----
    #pragma unroll
    for (int q = 0; q < 8; ++q){
      const float4 m0 = *(const float4*)&sM[0][q*4];
      const float4 m1 = *(const float4*)&sM[1][q*4];
      const float4 m2 = *(const float4*)&sM[2][q*4];
      const float4 m3 = *(const float4*)&sM[3][q*4];
      float val[4];
      #pragma unroll
      for (int jj = 0; jj < 4; ++jj){
        const int j = q*4 + jj;
        const float mqa = (jj==0) ? m0.x : (jj==1) ? m0.y : (jj==2) ? m0.z : m0.w;
        const float mqb = (jj==0) ? m1.x : (jj==1) ? m1.y : (jj==2) ? m1.z : m1.w;
        const float mqc = (jj==0) ? m2.x : (jj==1) ? m2.y : (jj==2) ? m2.z : m2.w;
        const float mqd = (jj==0) ? m3.x : (jj==1) ? m3.y : (jj==2) ? m3.z : m3.w;
        float o = bo[j] + w[0]*mqa + w[1]*mqb + w[2]*mqc + w[3]*mqd;
        #pragma unroll
        for (int k = 0; k < NFILT; ++k) o += h[k] * Wo[k*NFILT + j];
        const float th = fast_tanh(o);
        val[jj] = (th - bm[j]) * (g_[j] * rsqrtf(bv[j] + BN_EPS)) + be[j];
      }
      #pragma unroll
      for (int jj = 0; jj < 4; ++jj){
        const int j = q*4 + jj;
        const float* wrow = W_o0 + ((size_t)(l*NFILT + j)) * 48;
        #pragma unroll
        for (int n = 0; n < 48; ++n) acc[n] += val[jj] * wrow[n];
      }
      *(float4*)&sFeat[t][((q ^ sw) << 2)] = make_float4(val[0], val[1], val[2], val[3]);
    }
    // reload h from own row (no barrier: own row only)
    #pragma unroll
    for (int q = 0; q < 8; ++q){
      const float4 hv = *(const float4*)&sFeat[t][((q ^ sw) << 2)];
      h[4*q+0] = hv.x; h[4*q+1] = hv.y; h[4*q+2] = hv.z; h[4*q+3] = hv.w;
    }
  }

  // ---------------- head: relu(acc48) @ W_o1 + b_o1, relu ----------------
  {
    float o3[3] = {b_o1[0], b_o1[1], b_o1[2]};
    #pragma unroll
    for (int n = 0; n < 48; ++n){
      const float hn = fmaxf(acc[n], 0.f);
      o3[0] += hn * W_o1[n*3 + 0];
      o3[1] += hn * W_o1[n*3 + 1];
      o3[2] += hn * W_o1[n*3 + 2];
    }
    float* op = out + ((size_t)b * VV + v) * 3;
    op[0] = fmaxf(o3[0], 0.f);
    op[1] = fmaxf(o3[1], 0.f);
    op[2] = fmaxf(o3[2], 0.f);
  }
}

extern "C" void kernel_launch(void* const* d_in, const int* in_sizes, int n_in,
                              void* d_out, int out_size, void* d_ws, size_t ws_size,
                              hipStream_t stream) {
  const float* x      = (const float*)d_in[0];
  const float* bn0_g  = (const float*)d_in[1];
  const float* bn0_b  = (const float*)d_in[2];
  const float* bn0_m  = (const float*)d_in[3];
  const float* bn0_v  = (const float*)d_in[4];
  const float* W_in   = (const float*)d_in[5];
  const float* b_in   = (const float*)d_in[6];
  const float* W_flr  = (const float*)d_in[7];
  const float* b_flr  = (const float*)d_in[8];
  const float* W_s    = (const float*)d_in[9];
  const float* b_s    = (const float*)d_in[10];
  const float* W_out  = (const float*)d_in[11];
  const float* b_out  = (const float*)d_in[12];
  const float* bn_g   = (const float*)d_in[13];
  const float* bn_b   = (const float*)d_in[14];
  const float* bn_m   = (const float*)d_in[15];
  const float* bn_v   = (const float*)d_in[16];
  const float* W_o0   = (const float*)d_in[17];
  const float* b_o0   = (const float*)d_in[18];
  const float* W_o1   = (const float*)d_in[19];
  const float* b_o1   = (const float*)d_in[20];

  // reset pairwise sync flags (graph-capture-safe)
  hipMemsetAsync(d_ws, 0, BB * sizeof(int), stream);

  // 24 KB dynamic LDS pads static ~67 KB past 80 KB -> exactly 1 WG/CU,
  // so the 256 WGs spread across all 256 CUs.
  garnet_fused<<<dim3(BB * 2), dim3(TPB), 24 * 1024, stream>>>(
      x, bn0_g, bn0_b, bn0_m, bn0_v, W_in, b_in,
      W_flr, b_flr, W_s, b_s, W_out, b_out,
      bn_g, bn_b, bn_m, bn_v, W_o0, b_o0, W_o1, b_o1,
      (int*)d_ws, (float*)d_ws, (float*)d_out);
}